// Round 14
// baseline (2637.211 us; speedup 1.0000x reference)
//
#include <hip/hip_runtime.h>

#define HH 128
#define TT 1024
#define NFUT 64
#define MB 2
#define NBLK 256

typedef unsigned int u32;
typedef u32 u32x4 __attribute__((ext_vector_type(4)));
typedef _Float16 half2v __attribute__((ext_vector_type(2)));

__device__ __forceinline__ float sigm(float v) {
  return __builtin_amdgcn_rcpf(1.0f + __builtin_amdgcn_exp2f(v * -1.442695040888963f));
}
__device__ __forceinline__ float tanh_f(float v) {
  float a = __builtin_fabsf(v);
  float e = __builtin_amdgcn_exp2f(a * -2.885390081777927f);
  float r = (1.0f - e) * __builtin_amdgcn_rcpf(1.0f + e);
  return __builtin_copysignf(r, v);
}
__device__ __forceinline__ u32 pk2(float a, float b) {
  union { _Float16 h[2]; u32 u; } x;
  x.h[0] = (_Float16)a; x.h[1] = (_Float16)b;
  return x.u;
}
__device__ __forceinline__ u32x4 ldpk8(const float* __restrict__ p) {
  u32x4 r;
  r[0] = pk2(p[0], p[1]); r[1] = pk2(p[2], p[3]);
  r[2] = pk2(p[4], p[5]); r[3] = pk2(p[6], p[7]);
  return r;
}
__device__ __forceinline__ float d2(u32 h, u32 w, float a) {
  return __builtin_amdgcn_fdot2(__builtin_bit_cast(half2v, h),
                                __builtin_bit_cast(half2v, w), a, false);
}
#define D8(A, H, W) do { A = d2(H[0], W[0], A); A = d2(H[1], W[1], A); \
                         A = d2(H[2], W[2], A); A = d2(H[3], W[3], A); } while (0)

// Persistent 2-layer LSTM as a GEMV-pair via v_dot2_f32_f16 — NO MFMA.
// 256 WG x 512 thr (8 waves), MB=2 rows/WG.
//
// Why dot2 beats MFMA here (r1-r13 lessons): MB=2 wastes 14/16 MFMA rows;
// MFMA floor = 96 issues/SIMD/iter = 1862 cyc + parking/extract/repack tax
// (the 192-reg weight set exceeds the 128-arch half of the 256-reg budget ->
// v_accvgpr traffic or scratch spill in EVERY MFMA variant). dot2 does only
// the real work: 393216 MACs/WG/iter / 256 MAC/cyc/CU = 1536 cyc, weights are
// plain VGPRs (no AGPR semantics at all), results finalize in-lane on all 64
// lanes (1 h-value per lane, max transcendental spread, no repack).
//
// Lane decomposition: wave w, lane l: u = w*16+(l&15) [unit], kh = (l>>4)&1
// [K-half 64], gp = l>>5 [gate pair: 0={i,f}, 1={g,o}]; lane finalizes row
// b = gp. Weights/lane: 2 gates x 64 f16 x {W_hh1, W_hh2, W_ih2} = 48 u32x4
// = 192 VGPRs + ~45 working = ~237 < 256 budget (waves_per_eu(2,2)).
// Combine: 4x shfl_xor(16) sums K-halves; 2x shfl_xor(32) exchanges gate
// pairs (partner sends its opposite-b values); all in-wave, no LDS.
//
// Dataflow (2 barriers/iter): P1{x; cell1 dots; finalize h1(k); write} B1
// P2{cell2 dots on h2(k-1),h1(k); finalize h2(k); write; proj if k>=1023} B2.
// Future x-feedback: opart written in P2(k-1), read in P1(k) after B2 -> no
// extra barrier. k=1087 iteration only writes out[63] then breaks.
__global__
__attribute__((amdgpu_flat_work_group_size(512, 512), amdgpu_waves_per_eu(2, 2)))
void lstm_kernel(
    const float* __restrict__ x,
    const float* __restrict__ W_ih1, const float* __restrict__ b_ih1,
    const float* __restrict__ W_hh1, const float* __restrict__ b_hh1,
    const float* __restrict__ W_ih2, const float* __restrict__ b_ih2,
    const float* __restrict__ W_hh2, const float* __restrict__ b_hh2,
    const float* __restrict__ W_out, const float* __restrict__ b_out,
    float* __restrict__ out)
{
  __shared__ __align__(16) _Float16 h1L[2][2][HH];  // [buf][b][u]
  __shared__ __align__(16) _Float16 h2L[2][2][HH];
  __shared__ float xs[TT * MB];                     // [t][b]
  __shared__ float opart[8 * MB];

  const int tid = (int)threadIdx.x;
  const int lane = tid & 63;
  const int w = tid >> 6;
  const int ul = lane & 15;
  const int kh = (lane >> 4) & 1;
  const int gp = lane >> 5;
  const int u = w * 16 + ul;
  const int kh64 = kh * 64;
  const int b0g = (int)blockIdx.x * MB;

  for (int idx = tid; idx < TT * MB; idx += 512) {
    int t = idx >> 1, b = idx & 1;
    xs[idx] = x[(b0g + b) * TT + t];
  }
  ((_Float16*)h1L)[tid] = (_Float16)0.0f;   // 512 halfs = whole array
  ((_Float16*)h2L)[tid] = (_Float16)0.0f;

  // ---- 48 u32x4 weight registers (f16 pairs) ----
  const int q0 = gp * 2, q1 = q0 + 1;
  u32x4 W10_0,W10_1,W10_2,W10_3,W10_4,W10_5,W10_6,W10_7;
  u32x4 W11_0,W11_1,W11_2,W11_3,W11_4,W11_5,W11_6,W11_7;
  u32x4 W20_0,W20_1,W20_2,W20_3,W20_4,W20_5,W20_6,W20_7;
  u32x4 W21_0,W21_1,W21_2,W21_3,W21_4,W21_5,W21_6,W21_7;
  u32x4 W30_0,W30_1,W30_2,W30_3,W30_4,W30_5,W30_6,W30_7;
  u32x4 W31_0,W31_1,W31_2,W31_3,W31_4,W31_5,W31_6,W31_7;
#define LDALL(NM, MATP, Q) do { \
    const float* _b = (MATP) + ((Q) * HH + u) * HH + kh64; \
    NM##_0 = ldpk8(_b);      NM##_1 = ldpk8(_b + 8);  \
    NM##_2 = ldpk8(_b + 16); NM##_3 = ldpk8(_b + 24); \
    NM##_4 = ldpk8(_b + 32); NM##_5 = ldpk8(_b + 40); \
    NM##_6 = ldpk8(_b + 48); NM##_7 = ldpk8(_b + 56); } while (0)
  LDALL(W10, W_hh1, q0); LDALL(W11, W_hh1, q1);
  LDALL(W20, W_hh2, q0); LDALL(W21, W_hh2, q1);
  LDALL(W30, W_ih2, q0); LDALL(W31, W_ih2, q1);

  float bias1v[4], bias2v[4], wi1v[4];
#pragma unroll
  for (int q = 0; q < 4; ++q) {
    bias1v[q] = b_ih1[q * HH + u] + b_hh1[q * HH + u];
    bias2v[q] = b_ih2[q * HH + u] + b_hh2[q * HH + u];
    wi1v[q] = W_ih1[q * HH + u];
  }
  const float wo = W_out[u];
  const float bo = b_out[0];
  float c1 = 0.f, c2 = 0.f;  // state for (u, b=gp), every lane meaningful

  __syncthreads();

#define C1L(c) do { u32x4 H0 = hb0[c], H1 = hb1[c]; \
    D8(a00, H0, W10_##c); D8(a10, H0, W11_##c); \
    D8(a01, H1, W10_##c); D8(a11, H1, W11_##c); } while (0)
#define C2L(c) do { u32x4 H0 = hb0[c], H1 = hb1[c]; \
    D8(a00, H0, W20_##c); D8(a10, H0, W21_##c); \
    D8(a01, H1, W20_##c); D8(a11, H1, W21_##c); } while (0)
#define C3L(c) do { u32x4 H0 = jb0[c], H1 = jb1[c]; \
    D8(a00, H0, W30_##c); D8(a10, H0, W31_##c); \
    D8(a01, H1, W30_##c); D8(a11, H1, W31_##c); } while (0)
// combine K-halves + exchange gate pairs; leaves canonical gi,gf,gg,go
#define COMBINE() \
    a00 += __shfl_xor(a00, 16); a01 += __shfl_xor(a01, 16); \
    a10 += __shfl_xor(a10, 16); a11 += __shfl_xor(a11, 16); \
    float t0 = gp ? a00 : a01, t1 = gp ? a10 : a11; \
    float o0 = __shfl_xor(t0, 32), o1 = __shfl_xor(t1, 32); \
    float own0 = gp ? a01 : a00, own1 = gp ? a11 : a10; \
    float gi = gp ? o0 : own0, gf = gp ? o1 : own1; \
    float gg = gp ? own0 : o0, go = gp ? own1 : o1;

  for (int k = 0; k < TT + NFUT; ++k) {
    const int cur = k & 1;
    const int prv = cur ^ 1;

    // ---- x for step k (row b=gp) ----
    float xb;
    if (k < TT) {
      xb = xs[k * MB + gp];
    } else {
      float s = bo;
#pragma unroll
      for (int p = 0; p < 8; ++p) s += opart[p * MB + gp];
      xb = s;
      if (w == 0 && (lane & 31) == 0) out[(b0g + gp) * NFUT + (k - TT)] = s;
    }
    if (k == TT + NFUT - 1) break;  // k=1087: only out[63]

    // ---- P1: cell1 gates = h1(k-1) dot W_hh1 ----
    float a00 = 0.f, a01 = 0.f, a10 = 0.f, a11 = 0.f;
    {
      const u32x4* hb0 = (const u32x4*)&h1L[prv][0][kh64];
      const u32x4* hb1 = (const u32x4*)&h1L[prv][1][kh64];
      C1L(0); C1L(1); C1L(2); C1L(3); C1L(4); C1L(5); C1L(6); C1L(7);
    }
    {
      COMBINE();
      gi += xb * wi1v[0] + bias1v[0];
      gf += xb * wi1v[1] + bias1v[1];
      gg += xb * wi1v[2] + bias1v[2];
      go += xb * wi1v[3] + bias1v[3];
      c1 = sigm(gf) * c1 + sigm(gi) * tanh_f(gg);
      float h = sigm(go) * tanh_f(c1);
      if (kh == 0) h1L[cur][gp][u] = (_Float16)h;
    }
    __syncthreads();  // B1: publish h1(k)

    // ---- P2: cell2 gates = h2(k-1) dot W_hh2 + h1(k) dot W_ih2 ----
    a00 = 0.f; a01 = 0.f; a10 = 0.f; a11 = 0.f;
    {
      const u32x4* hb0 = (const u32x4*)&h2L[prv][0][kh64];
      const u32x4* hb1 = (const u32x4*)&h2L[prv][1][kh64];
      C2L(0); C2L(1); C2L(2); C2L(3); C2L(4); C2L(5); C2L(6); C2L(7);
      const u32x4* jb0 = (const u32x4*)&h1L[cur][0][kh64];
      const u32x4* jb1 = (const u32x4*)&h1L[cur][1][kh64];
      C3L(0); C3L(1); C3L(2); C3L(3); C3L(4); C3L(5); C3L(6); C3L(7);
    }
    {
      COMBINE();
      gi += bias2v[0];
      gf += bias2v[1];
      gg += bias2v[2];
      go += bias2v[3];
      c2 = sigm(gf) * c2 + sigm(gi) * tanh_f(gg);
      float h = sigm(go) * tanh_f(c2);
      if (kh == 0) h2L[cur][gp][u] = (_Float16)h;
      if (k >= TT - 1) {
        float p = h * wo;
        p += __shfl_xor(p, 1);
        p += __shfl_xor(p, 2);
        p += __shfl_xor(p, 4);
        p += __shfl_xor(p, 8);
        if (ul == 0 && kh == 0) opart[w * MB + gp] = p;
      }
    }
    __syncthreads();  // B2: publish h2(k), opart
  }
}

extern "C" void kernel_launch(void* const* d_in, const int* in_sizes, int n_in,
                              void* d_out, int out_size, void* d_ws, size_t ws_size,
                              hipStream_t stream) {
  const float* x     = (const float*)d_in[0];
  const float* W_ih1 = (const float*)d_in[1];
  const float* b_ih1 = (const float*)d_in[2];
  const float* W_hh1 = (const float*)d_in[3];
  const float* b_hh1 = (const float*)d_in[4];
  const float* W_ih2 = (const float*)d_in[5];
  const float* b_ih2 = (const float*)d_in[6];
  const float* W_hh2 = (const float*)d_in[7];
  const float* b_hh2 = (const float*)d_in[8];
  const float* W_out = (const float*)d_in[9];
  const float* b_out = (const float*)d_in[10];
  (void)in_sizes; (void)n_in; (void)out_size; (void)d_ws; (void)ws_size;

  lstm_kernel<<<dim3(NBLK), dim3(512), 0, stream>>>(
      x, W_ih1, b_ih1, W_hh1, b_hh1, W_ih2, b_ih2, W_hh2, b_hh2, W_out, b_out,
      (float*)d_out);
}

// Round 15
// 1605.479 us; speedup vs baseline: 1.6426x; 1.6426x over previous
//
#include <hip/hip_runtime.h>

#define HH 128
#define TT 1024
#define NFUT 64
#define MB 2
#define NBLK 256
#define NITER (TT + NFUT - 1)  // i=1023 -> out[0], i=1086 -> out[63]

typedef _Float16 half8 __attribute__((ext_vector_type(8)));
typedef float floatx4 __attribute__((ext_vector_type(4)));

#define MFMA16(a, b, c) __builtin_amdgcn_mfma_f32_16x16x32_f16((a), (b), (c), 0, 0, 0)

__device__ __forceinline__ float sigm(float v) {
  return __builtin_amdgcn_rcpf(1.0f + __builtin_amdgcn_exp2f(v * -1.442695040888963f));
}
__device__ __forceinline__ float tanh_f(float v) {
  float a = __builtin_fabsf(v);
  float e = __builtin_amdgcn_exp2f(a * -2.885390081777927f);
  float r = (1.0f - e) * __builtin_amdgcn_rcpf(1.0f + e);
  return __builtin_copysignf(r, v);
}
__device__ __forceinline__ half8 ldw8(const float* __restrict__ p) {
  half8 r;
#pragma unroll
  for (int i = 0; i < 8; ++i) r[i] = (_Float16)p[i];
  return r;
}

// Persistent 2-layer LSTM, 256 WG x 512 thr (8 waves), MB=2 rows/WG.
// == the 1523us champion structure (sequential, 1 barrier/encoder step,
// zero-init accs, in-lane finalize) + pipe-overlap surgery ==
//
// REGISTER LAW (r1-r14): arch budget = 256/(waves/SIMD); AGPR same; VALU
// reads arch only; MFMA B reads AGPR natively. At 8 waves (2 wps) the 192-reg
// weight set fits ONLY as ~128 AGPR + 64 arch with MFMA consuming B from
// AGPR -- this config (r8=1523us, 56B/thr residual spill) is the unique
// resident point. s_barrier = scheduling-region boundary: sequential {P1} B
// {P2} keeps acc sets in separate regions (no spill); fused single-region
// variants balloon regalloc (r9-r13: 40-122MB WRITE). DO NOT FUSE.
//
// THIS ROUND: attack serialization (MfmaUtil 45 + VALUBusy 53 -> pipes
// alternate). (1) HALF-BURSTS {i,g} then {f,o}: sigm(i)*tanh(g) is
// independent of the second burst -> scheduler can issue it into the {f,o}
// MFMA shadow (XDL/VALU dual-pipe, intra-wave). Acc liveness still <= 4 accs.
// (2) setprio(1) around bursts: biases the 2 waves/SIMD into anti-phase so
// one wave's MFMAs cover the other's finalize VALU.
__global__
__attribute__((amdgpu_flat_work_group_size(512, 512), amdgpu_waves_per_eu(2, 2)))
void lstm_kernel(
    const float* __restrict__ x,
    const float* __restrict__ W_ih1, const float* __restrict__ b_ih1,
    const float* __restrict__ W_hh1, const float* __restrict__ b_hh1,
    const float* __restrict__ W_ih2, const float* __restrict__ b_ih2,
    const float* __restrict__ W_hh2, const float* __restrict__ b_hh2,
    const float* __restrict__ W_out, const float* __restrict__ b_out,
    float* __restrict__ out)
{
  __shared__ __align__(16) _Float16 h1b[2][2048];  // A-frag order; rows>=MB stay 0
  __shared__ __align__(16) _Float16 h2b[2][2048];
  __shared__ __align__(16) _Float16 xs[TT * MB];   // [t][b]
  __shared__ float opart[8 * MB];

  const int tid = (int)threadIdx.x;
  const int lane = tid & 63;
  const int w = tid >> 6;
  const int jl = lane & 15;
  const int rg = lane >> 4;
  const int j = w * 16 + jl;
  const int b0g = (int)blockIdx.x * MB;

  for (int idx = tid; idx < TT * MB; idx += 512) {
    int t = idx & (TT - 1);
    int bb = idx >> 10;
    xs[t * MB + bb] = (_Float16)x[(b0g + bb) * TT + t];
  }
  for (int idx = tid; idx < 2 * 2048; idx += 512) {
    h1b[idx >> 11][idx & 2047] = (_Float16)0.0f;
    h2b[idx >> 11][idx & 2047] = (_Float16)0.0f;
  }

  // ---- 48 named weight B-fragments: A=W_hh1, H=W_hh2, I=W_ih2 ----
  // first digit = gate (0=i,1=f,2=g,3=o), second = kf
  half8 A00, A01, A02, A03, A10, A11, A12, A13, A20, A21, A22, A23, A30, A31, A32, A33;
  half8 H00, H01, H02, H03, H10, H11, H12, H13, H20, H21, H22, H23, H30, H31, H32, H33;
  half8 I00, I01, I02, I03, I10, I11, I12, I13, I20, I21, I22, I23, I30, I31, I32, I33;
#define LDW(N, Q, P) do { \
    const float* _p = (P) + ((Q) * HH + j) * HH + rg * 8; \
    N##0 = ldw8(_p);      N##1 = ldw8(_p + 32); \
    N##2 = ldw8(_p + 64); N##3 = ldw8(_p + 96); } while (0)
  LDW(A0, 0, W_hh1); LDW(A1, 1, W_hh1); LDW(A2, 2, W_hh1); LDW(A3, 3, W_hh1);
  LDW(H0, 0, W_hh2); LDW(H1, 1, W_hh2); LDW(H2, 2, W_hh2); LDW(H3, 3, W_hh2);
  LDW(I0, 0, W_ih2); LDW(I1, 1, W_ih2); LDW(I2, 2, W_ih2); LDW(I3, 3, W_ih2);

  float bias1[4], bias2[4], wi1[4];
#pragma unroll
  for (int q = 0; q < 4; ++q) {
    bias1[q] = b_ih1[q * HH + j] + b_hh1[q * HH + j];
    bias2[q] = b_ih2[q * HH + j] + b_hh2[q * HH + j];
    wi1[q] = W_ih1[q * HH + j];
  }
  const float wo = W_out[j];
  const float bo = b_out[0];
  float c1a = 0.f, c1b = 0.f, c2a = 0.f, c2b = 0.f;  // lanes 0-15 meaningful

  __syncthreads();

  const int aoff = lane * 8;
  const int wb = ((j >> 5) << 9) + (((j >> 3) & 3) << 7) + (j & 7);

  // half-burst macros: two gates GA,GB into p0,p1
#define C1H(KF, GA, GB) do { \
    half8 av = *(const half8*)(&h1b[cur][KF * 512 + aoff]); \
    p0 = MFMA16(av, A##GA##KF, p0); p1 = MFMA16(av, A##GB##KF, p1); } while (0)
#define C2H(KF, GA, GB) do { \
    half8 av = *(const half8*)(&h2b[cur][KF * 512 + aoff]); \
    p0 = MFMA16(av, H##GA##KF, p0); p1 = MFMA16(av, H##GB##KF, p1); \
    half8 aw = *(const half8*)(&h1b[nxt][KF * 512 + aoff]); \
    p0 = MFMA16(aw, I##GA##KF, p0); p1 = MFMA16(aw, I##GB##KF, p1); } while (0)

  for (int i = 0; i < NITER; ++i) {
    const int cur = i & 1;
    const int nxt = cur ^ 1;

    // ---- x for this step (uniform; LDS broadcast reads) ----
    float x0, x1;
    if (i < TT) {
      x0 = (float)xs[i * MB + 0];
      x1 = (float)xs[i * MB + 1];
    } else {
      float s0 = bo, s1 = bo;
#pragma unroll
      for (int p = 0; p < 8; ++p) {
        s0 += opart[p * MB + 0];
        s1 += opart[p * MB + 1];
      }
      x0 = s0; x1 = s1;
    }

    // ---- phase 1, half A: gates {i,g} of cell1 ----
    floatx4 p0 = {0.f,0.f,0.f,0.f}, p1 = {0.f,0.f,0.f,0.f};
    __builtin_amdgcn_s_setprio(1);
    C1H(0, 0, 2); C1H(1, 0, 2); C1H(2, 0, 2); C1H(3, 0, 2);
    __builtin_amdgcn_s_setprio(0);
    // early transcendentals (independent of half B -> fill its MFMA shadow)
    float gi0 = p0[0] + x0 * wi1[0] + bias1[0], gi1 = p0[1] + x1 * wi1[0] + bias1[0];
    float gg0 = p1[0] + x0 * wi1[2] + bias1[2], gg1 = p1[1] + x1 * wi1[2] + bias1[2];
    float tig0 = sigm(gi0) * tanh_f(gg0);
    float tig1 = sigm(gi1) * tanh_f(gg1);

    // ---- phase 1, half B: gates {f,o} + finalize -> h1(i) ----
    p0 = (floatx4){0.f,0.f,0.f,0.f}; p1 = (floatx4){0.f,0.f,0.f,0.f};
    __builtin_amdgcn_s_setprio(1);
    C1H(0, 1, 3); C1H(1, 1, 3); C1H(2, 1, 3); C1H(3, 1, 3);
    __builtin_amdgcn_s_setprio(0);
    {
      float gf0 = p0[0] + x0 * wi1[1] + bias1[1], gf1 = p0[1] + x1 * wi1[1] + bias1[1];
      float go0 = p1[0] + x0 * wi1[3] + bias1[3], go1 = p1[1] + x1 * wi1[3] + bias1[3];
      c1a = sigm(gf0) * c1a + tig0;
      c1b = sigm(gf1) * c1b + tig1;
      float h10 = sigm(go0) * tanh_f(c1a);
      float h11 = sigm(go1) * tanh_f(c1b);
      if (lane < 16) {
        h1b[nxt][wb] = (_Float16)h10;
        h1b[nxt][wb + 8] = (_Float16)h11;
      }
    }
    __syncthreads();  // the ONE barrier: publishes h1(i)

    // ---- phase 2, half A: gates {i,g} of cell2 ----
    p0 = (floatx4){0.f,0.f,0.f,0.f}; p1 = (floatx4){0.f,0.f,0.f,0.f};
    __builtin_amdgcn_s_setprio(1);
    C2H(0, 0, 2); C2H(1, 0, 2); C2H(2, 0, 2); C2H(3, 0, 2);
    __builtin_amdgcn_s_setprio(0);
    float hi0 = p0[0] + bias2[0], hi1 = p0[1] + bias2[0];
    float hg0 = p1[0] + bias2[2], hg1 = p1[1] + bias2[2];
    float tig20 = sigm(hi0) * tanh_f(hg0);
    float tig21 = sigm(hi1) * tanh_f(hg1);

    // ---- phase 2, half B: gates {f,o} + finalize -> h2(i) ----
    p0 = (floatx4){0.f,0.f,0.f,0.f}; p1 = (floatx4){0.f,0.f,0.f,0.f};
    __builtin_amdgcn_s_setprio(1);
    C2H(0, 1, 3); C2H(1, 1, 3); C2H(2, 1, 3); C2H(3, 1, 3);
    __builtin_amdgcn_s_setprio(0);
    {
      float hf0 = p0[0] + bias2[1], hf1 = p0[1] + bias2[1];
      float ho0 = p1[0] + bias2[3], ho1 = p1[1] + bias2[3];
      c2a = sigm(hf0) * c2a + tig20;
      c2b = sigm(hf1) * c2b + tig21;
      float h20 = sigm(ho0) * tanh_f(c2a);
      float h21 = sigm(ho1) * tanh_f(c2b);
      if (lane < 16) {
        h2b[nxt][wb] = (_Float16)h20;
        h2b[nxt][wb + 8] = (_Float16)h21;
      }
      if (i >= TT - 1) {
        float q0 = h20 * wo, q1 = h21 * wo;
        q0 += __shfl_xor(q0, 1); q1 += __shfl_xor(q1, 1);
        q0 += __shfl_xor(q0, 2); q1 += __shfl_xor(q1, 2);
        q0 += __shfl_xor(q0, 4); q1 += __shfl_xor(q1, 4);
        q0 += __shfl_xor(q0, 8); q1 += __shfl_xor(q1, 8);
        if (lane == 0) {
          opart[w * MB + 0] = q0;
          opart[w * MB + 1] = q1;
        }
      }
    }

    if (i >= TT - 1) {
      __syncthreads();  // publish opart (future feedback + out write)
      if (w == 0 && lane < MB) {
        float s = bo;
#pragma unroll
        for (int p = 0; p < 8; ++p) s += opart[p * MB + lane];
        out[(b0g + lane) * NFUT + (i - (TT - 1))] = s;
      }
    }
    // pin the P2 -> P1(i+1) seam (prevents cross-region acc co-liveness)
    __builtin_amdgcn_sched_barrier(0);
  }
}

extern "C" void kernel_launch(void* const* d_in, const int* in_sizes, int n_in,
                              void* d_out, int out_size, void* d_ws, size_t ws_size,
                              hipStream_t stream) {
  const float* x     = (const float*)d_in[0];
  const float* W_ih1 = (const float*)d_in[1];
  const float* b_ih1 = (const float*)d_in[2];
  const float* W_hh1 = (const float*)d_in[3];
  const float* b_hh1 = (const float*)d_in[4];
  const float* W_ih2 = (const float*)d_in[5];
  const float* b_ih2 = (const float*)d_in[6];
  const float* W_hh2 = (const float*)d_in[7];
  const float* b_hh2 = (const float*)d_in[8];
  const float* W_out = (const float*)d_in[9];
  const float* b_out = (const float*)d_in[10];
  (void)in_sizes; (void)n_in; (void)out_size; (void)d_ws; (void)ws_size;

  lstm_kernel<<<dim3(NBLK), dim3(512), 0, stream>>>(
      x, W_ih1, b_ih1, W_hh1, b_hh1, W_ih2, b_ih2, W_hh2, b_hh2, W_out, b_out,
      (float*)d_out);
}